// Round 5
// baseline (181.648 us; speedup 1.0000x reference)
//
#include <hip/hip_runtime.h>

// ---- MFMA fragment layouts (gfx950, 16x16 family, verified m89) ----
// A-frag (M16,K32): lane l holds A[row=l&15][k=(l>>4)*8+e], e=0..7
// B-frag (K32,N16): lane l holds B[k=(l>>4)*8+e][col=l&15]
// C/D:              col=l&15, row=(l>>4)*4+reg
// K=16 variants: same with 4 elems, k=(l>>4)*4+e.
//
// Swapped scores: S^T = mfma(A=h_j, B=G_i), G_i[d][i]=h[i][d]*A_k[d]
//   -> lane holds S[i=ll][j=lg*4+r].
// PV: out^T = mfma(A=hT_frag, B=P): score C-frag IS the PV B-frag; P stays
// in registers. hT fragments (hf[t][e] = h[j0+lg*4+e][t*16+ll]) are loaded
// from GLOBAL H (fp32, L2/L3-resident) and cvt'd to f16 — no second LDS
// copy, no tr_read. LDS = 74 KB -> 2 blocks/CU.

typedef _Float16 half8 __attribute__((ext_vector_type(8)));
typedef _Float16 half4 __attribute__((ext_vector_type(4)));
typedef float f32x4 __attribute__((ext_vector_type(4)));

constexpr int B_ = 256, N_ = 300, E_ = 100;
constexpr int HS = 120;            // h16 row stride (halves)
constexpr float NEGINF = -9e15f;   // reference mask value
constexpr float PADV   = -3e38f;   // padding: exp(PADV - m) == 0 even vs NEGINF

// LDS: h16 [304][120] f16 @0 (72960 B) | A16 [4][128] f16 @72960 (1024 B)
constexpr int LDS_BYTES = 72960 + 1024;   // 73984 -> 2 blocks/CU

__global__ __launch_bounds__(512, 4)
void gat_flash3(const float* __restrict__ H, const int* __restrict__ ADJ,
                const float* __restrict__ A, float* __restrict__ OUT) {
  extern __shared__ char smraw[];
  _Float16* h16 = (_Float16*)smraw;                 // [304][HS]
  _Float16* A16 = (_Float16*)(smraw + 72960);       // [4][128]

  const int bid = blockIdx.x;
  const int b = bid >> 1, q = bid & 1;              // 2 blocks per batch
  const int tid = threadIdx.x;
  const int w = tid >> 6, lane = tid & 63;
  const int lg = lane >> 4, ll = lane & 15;

  const float* Hb  = H + (size_t)b * (N_ * E_);
  const int*   AJb = ADJ + (size_t)b * (N_ * N_);

  // ---------------- stage h16 [j][d], zero-padded 304x120 ----------------
  for (int u = tid; u < 304 * 15; u += 512) {
    const int j = u / 15, oct = u % 15;
    half8 v;
#pragma unroll
    for (int e = 0; e < 8; ++e) {
      const int d = oct * 8 + e;
      v[e] = (_Float16)((j < N_ && d < E_) ? Hb[j * E_ + d] : 0.f);
    }
    *(half8*)&h16[j * HS + oct * 8] = v;
  }
  // ---------------- stage A16 [4][128] -----------------------------------
  if (tid < 64) {
    const int k = tid >> 4, oct = tid & 15;
    half8 v;
#pragma unroll
    for (int e = 0; e < 8; ++e) {
      const int d = oct * 8 + e;
      v[e] = (_Float16)((d < E_) ? A[k * E_ + d] : 0.f);
    }
    *(half8*)&A16[k * 128 + oct * 8] = v;
  }
  __syncthreads();   // the ONLY barrier

  // ============ per-wave independent 16-row i-strips (even/odd split) =====
  for (int tl = w; q + 2 * tl < 19; tl += 8) {
    const int s    = q + 2 * tl;
    const int irow = s * 16 + ll;
    const int irc  = irow < N_ ? irow : N_ - 1;

    // ---- G = h_i (.) A_k octets (B-operand fragments), per strip ----
    half8 g[3][4];
    half4 gt[4];
#pragma unroll
    for (int db = 0; db < 3; ++db) {
      const int e8 = db * 32 + lg * 8;
      const half8 hi = *(const half8*)&h16[irow * HS + e8];
#pragma unroll
      for (int k = 0; k < 4; ++k)
        g[db][k] = hi * *(const half8*)&A16[k * 128 + e8];
    }
    {
      const int e4 = 96 + lg * 4;
      const half4 hit = *(const half4*)&h16[irow * HS + e4];
#pragma unroll
      for (int k = 0; k < 4; ++k)
        gt[k] = hit * *(const half4*)&A16[k * 128 + e4];
    }

    float m = PADV, lsum = 0.f;
    f32x4 acc[7];
#pragma unroll
    for (int t = 0; t < 7; ++t) acc[t] = (f32x4){0.f, 0.f, 0.f, 0.f};

    const int* ajrow = AJb + (size_t)irc * N_;
    int4 av = *(const int4*)(ajrow + lg * 4);

    for (int jt = 0; jt < 19; ++jt) {
      const int j0 = jt * 16;
      // ---- next tile's adj chunk (clamped; jt==18/lg==3 overridden) ----
      int4 avn = av;
      if (jt < 18) {
        int jc = j0 + 16 + lg * 4;
        if (jc > N_ - 4) jc = N_ - 4;
        avn = *(const int4*)(ajrow + jc);
      }

      // ---- scores: S^T tile, 4 edge-type accumulators ----
      f32x4 c0 = {0.f, 0.f, 0.f, 0.f}, c1 = c0, c2 = c0, c3 = c0;
      const int jrow = j0 + ll;
#pragma unroll
      for (int db = 0; db < 3; ++db) {
        const half8 aj = *(const half8*)&h16[jrow * HS + db * 32 + lg * 8];
        c0 = __builtin_amdgcn_mfma_f32_16x16x32_f16(aj, g[db][0], c0, 0, 0, 0);
        c1 = __builtin_amdgcn_mfma_f32_16x16x32_f16(aj, g[db][1], c1, 0, 0, 0);
        c2 = __builtin_amdgcn_mfma_f32_16x16x32_f16(aj, g[db][2], c2, 0, 0, 0);
        c3 = __builtin_amdgcn_mfma_f32_16x16x32_f16(aj, g[db][3], c3, 0, 0, 0);
      }
      {
        const half4 ajt = *(const half4*)&h16[jrow * HS + 96 + lg * 4];
        c0 = __builtin_amdgcn_mfma_f32_16x16x16f16(ajt, gt[0], c0, 0, 0, 0);
        c1 = __builtin_amdgcn_mfma_f32_16x16x16f16(ajt, gt[1], c1, 0, 0, 0);
        c2 = __builtin_amdgcn_mfma_f32_16x16x16f16(ajt, gt[2], c2, 0, 0, 0);
        c3 = __builtin_amdgcn_mfma_f32_16x16x16f16(ajt, gt[3], c3, 0, 0, 0);
      }

      // ---- select by adj + leaky-relu + mask ----
      const int va[4] = {av.x, av.y, av.z, av.w};
      float sv[4];
#pragma unroll
      for (int r = 0; r < 4; ++r) {
        const float e = (va[r] == 1) ? c0[r] : (va[r] == 2) ? c1[r]
                       : (va[r] == 3) ? c2[r] : c3[r];
        sv[r] = (va[r] == 0) ? NEGINF : fmaxf(e, 0.2f * e);
      }
      if (jt == 18 && lg == 3) { sv[0] = PADV; sv[1] = PADV; sv[2] = PADV; sv[3] = PADV; }
      av = avn;

      // ---- PV h^T fragments from global (fp32 -> f16), c0..c3 now dead ----
      half4 hf[7];
      if (jt < 18) {
        const float* hb0 = Hb + (size_t)(j0 + lg * 4) * E_ + ll;
#pragma unroll
        for (int t = 0; t < 6; ++t) {
          const float f0 = hb0[t * 16];
          const float f1 = hb0[t * 16 + E_];
          const float f2 = hb0[t * 16 + 2 * E_];
          const float f3 = hb0[t * 16 + 3 * E_];
          hf[t][0] = (_Float16)f0; hf[t][1] = (_Float16)f1;
          hf[t][2] = (_Float16)f2; hf[t][3] = (_Float16)f3;
        }
        {   // t = 6: col clamp (ll > 3 feeds only unstored e >= 100 rows)
          const int col = (96 + ll < E_) ? 96 + ll : E_ - 1;
          const float* p = Hb + (size_t)(j0 + lg * 4) * E_ + col;
          const float f0 = p[0], f1 = p[E_], f2 = p[2 * E_], f3 = p[3 * E_];
          hf[6][0] = (_Float16)f0; hf[6][1] = (_Float16)f1;
          hf[6][2] = (_Float16)f2; hf[6][3] = (_Float16)f3;
        }
      } else {   // jt == 18: j clamp (clamped j's have p == 0)
#pragma unroll
        for (int t = 0; t < 7; ++t) {
          const int col = (t * 16 + ll < E_) ? t * 16 + ll : E_ - 1;
#pragma unroll
          for (int e = 0; e < 4; ++e) {
            int j = j0 + lg * 4 + e;
            if (j > N_ - 1) j = N_ - 1;
            hf[t][e] = (_Float16)Hb[(size_t)j * E_ + col];
          }
        }
      }

      // ---- online softmax (m shared across the 4 lane-groups of this i) ----
      float tmax = fmaxf(fmaxf(sv[0], sv[1]), fmaxf(sv[2], sv[3]));
      tmax = fmaxf(tmax, __shfl_xor(tmax, 16));
      tmax = fmaxf(tmax, __shfl_xor(tmax, 32));
      if (tmax > m) {
        const float f = __expf(m - tmax);
        m = tmax;
        lsum *= f;
#pragma unroll
        for (int t = 0; t < 7; ++t) {
          acc[t][0] *= f; acc[t][1] *= f; acc[t][2] *= f; acc[t][3] *= f;
        }
      }
      const float p0 = __expf(sv[0] - m), p1 = __expf(sv[1] - m);
      const float p2 = __expf(sv[2] - m), p3 = __expf(sv[3] - m);
      lsum += (p0 + p1) + (p2 + p3);
      half4 pb;
      pb[0] = (_Float16)p0; pb[1] = (_Float16)p1;
      pb[2] = (_Float16)p2; pb[3] = (_Float16)p3;

      // ---- PV: acc[e-tile] += hT_frag x P ----
#pragma unroll
      for (int t = 0; t < 7; ++t)
        acc[t] = __builtin_amdgcn_mfma_f32_16x16x16f16(hf[t], pb, acc[t], 0, 0, 0);
    }

    // ---- epilogue: normalize + store ----
    lsum += __shfl_xor(lsum, 16);
    lsum += __shfl_xor(lsum, 32);
    const float rv = 1.f / lsum;
    if (irow < N_) {
      float* orow = OUT + ((size_t)b * N_ + irow) * E_;
#pragma unroll
      for (int t = 0; t < 7; ++t) {
        const int e0 = t * 16 + lg * 4;
        if (e0 < E_) {
          f32x4 o = acc[t];
          o[0] *= rv; o[1] *= rv; o[2] *= rv; o[3] *= rv;
          *(f32x4*)&orow[e0] = o;
        }
      }
    }
  }
}

extern "C" void kernel_launch(void* const* d_in, const int* in_sizes, int n_in,
                              void* d_out, int out_size, void* d_ws, size_t ws_size,
                              hipStream_t stream) {
  const float* H  = (const float*)d_in[0];
  const int*   AJ = (const int*)d_in[1];
  const float* A  = (const float*)d_in[2];
  float* OUT = (float*)d_out;

  (void)hipFuncSetAttribute(reinterpret_cast<const void*>(gat_flash3),
                            hipFuncAttributeMaxDynamicSharedMemorySize,
                            LDS_BYTES);
  gat_flash3<<<2 * B_, 512, LDS_BYTES, stream>>>(H, AJ, A, OUT);
}

// Round 6
// 105.110 us; speedup vs baseline: 1.7282x; 1.7282x over previous
//
#include <hip/hip_runtime.h>

// MFMA fragment layouts (gfx950, 16x16 family, verified m89):
//   A-frag (M16,K32): lane l holds A[row=l&15][k=(l>>4)*8+e], e=0..7
//   B-frag (K32,N16): lane l holds B[k=(l>>4)*8+e][col=l&15]
//   C/D:              col=l&15, row=(l>>4)*4+reg
//   K=16 variants: same with 4 elems, k=(l>>4)*4+e.
//
// h stored subtiled: hS[jt][et][j'][d'] = h[16*jt+j'][16*et+d'] (16x16 f16 = 512 B).
// ds_read_b64_tr_b16 model (m156+m162 reconciled): each lane fetches its own
// 64b; HW redistributes within each 16-lane group (4x16 block transpose of the
// group's 128 B). Addressing: lane (lg,ll) addr = subtile + lg*128 + ll*8;
// lane ll receives column ll: elem e = subtile[lg*4+e][ll] = h[j0+lg*4+e][e0+ll].
// (v4 used ll*2 — wrong model, unaligned — hence its absmax 7.4.)

typedef _Float16 half8 __attribute__((ext_vector_type(8)));
typedef _Float16 half4 __attribute__((ext_vector_type(4)));
typedef float f32x4 __attribute__((ext_vector_type(4)));

constexpr int B_ = 256, N_ = 300, E_ = 100;
constexpr float NEGINF = -9e15f;   // reference mask value
constexpr float PADV   = -3e38f;   // padding: exp(PADV - m) == 0 even vs NEGINF max

// LDS: hS subtiled [19][7][16][16] f16 = 68096 B @0 | A16 [4][128] f16 @68096 (1024 B)
constexpr int LDS_BYTES = 68096 + 1024;   // 69120 -> 2 blocks/CU

__global__ __launch_bounds__(512, 4)
void gat_flash4(const float* __restrict__ H, const int* __restrict__ ADJ,
                const float* __restrict__ A, float* __restrict__ OUT) {
  extern __shared__ char smraw[];
  _Float16* hS  = (_Float16*)smraw;
  _Float16* A16 = (_Float16*)(smraw + 68096);

  const int bid = blockIdx.x;
  const int b = bid >> 1, q = bid & 1;          // 2 blocks per batch (even/odd strips)
  const int tid = threadIdx.x;
  const int w = tid >> 6, lane = tid & 63;
  const int lg = lane >> 4, ll = lane & 15;

  const float* Hb  = H + (size_t)b * (N_ * E_);
  const int*   AJb = ADJ + (size_t)b * (N_ * N_);

  // ---------------- stage h into subtiled LDS (zero-padded) ----------------
  for (int u = tid; u < 304 * 14; u += 512) {
    const int j = u / 14, hr = u % 14;          // hr: 8-half chunk of d (d = hr*8+e)
    half8 v;
#pragma unroll
    for (int e = 0; e < 8; ++e) {
      const int d = hr * 8 + e;
      v[e] = (_Float16)((j < N_ && d < E_) ? Hb[j * E_ + d] : 0.f);
    }
    *(half8*)&hS[(((j >> 4) * 7 + (hr >> 1)) << 8) + ((j & 15) << 4) + ((hr & 1) << 3)] = v;
  }
  if (tid < 64) {
    const int k = tid >> 4, oct = tid & 15;
    half8 v;
#pragma unroll
    for (int e = 0; e < 8; ++e) {
      const int d = oct * 8 + e;
      v[e] = (_Float16)((d < E_) ? A[k * E_ + d] : 0.f);
    }
    *(half8*)&A16[k * 128 + oct * 8] = v;
  }
  __syncthreads();   // only barrier

  const unsigned ldsbase = (unsigned)(size_t)(void*)hS;     // low 32b = LDS offset
  const unsigned trlane  = (unsigned)(ll * 8 + lg * 128);   // natural per-lane addr

  // ============ per-wave independent 16-row i-strips (even/odd split) ======
  for (int tl = w; q + 2 * tl < 19; tl += 8) {
    const int s    = q + 2 * tl;
    const int irow = s * 16 + ll;
    const int irc  = irow < N_ ? irow : N_ - 1;

    // ---- G = h_i (.) A_k octets (B-operand fragments), per strip ----
    half8 g[3][4];
    half4 gt[4];
#pragma unroll
    for (int db = 0; db < 3; ++db) {
      const int doct = db * 4 + lg;
      const half8 hi = *(const half8*)&hS[((s * 7 + (doct >> 1)) << 8) + (ll << 4) + ((doct & 1) << 3)];
#pragma unroll
      for (int k = 0; k < 4; ++k)
        g[db][k] = hi * *(const half8*)&A16[k * 128 + doct * 8];
    }
    {
      const half4 hit = *(const half4*)&hS[((s * 7 + 6) << 8) + (ll << 4) + lg * 4];
#pragma unroll
      for (int k = 0; k < 4; ++k)
        gt[k] = hit * *(const half4*)&A16[k * 128 + 96 + lg * 4];
    }

    float m = PADV, lsum = 0.f;
    f32x4 acc[7];
#pragma unroll
    for (int t = 0; t < 7; ++t) acc[t] = (f32x4){0.f, 0.f, 0.f, 0.f};

    const int* ajrow = AJb + (size_t)irc * N_;
    int4 av = *(const int4*)(ajrow + lg * 4);

    for (int jt = 0; jt < 19; ++jt) {
      // ---- next tile's adj chunk (clamped; jt==18/lg==3 overridden) ----
      int4 avn = av;
      if (jt < 18) {
        int jc = jt * 16 + 16 + lg * 4;
        if (jc > N_ - 4) jc = N_ - 4;
        avn = *(const int4*)(ajrow + jc);
      }

      // ---- scores: S^T tile, 4 edge-type accumulators ----
      f32x4 c0 = {0.f, 0.f, 0.f, 0.f}, c1 = c0, c2 = c0, c3 = c0;
#pragma unroll
      for (int db = 0; db < 3; ++db) {
        const int doct = db * 4 + lg;
        const half8 aj = *(const half8*)&hS[((jt * 7 + (doct >> 1)) << 8) + (ll << 4) + ((doct & 1) << 3)];
        c0 = __builtin_amdgcn_mfma_f32_16x16x32_f16(aj, g[db][0], c0, 0, 0, 0);
        c1 = __builtin_amdgcn_mfma_f32_16x16x32_f16(aj, g[db][1], c1, 0, 0, 0);
        c2 = __builtin_amdgcn_mfma_f32_16x16x32_f16(aj, g[db][2], c2, 0, 0, 0);
        c3 = __builtin_amdgcn_mfma_f32_16x16x32_f16(aj, g[db][3], c3, 0, 0, 0);
      }
      {
        const half4 ajt = *(const half4*)&hS[((jt * 7 + 6) << 8) + (ll << 4) + lg * 4];
        c0 = __builtin_amdgcn_mfma_f32_16x16x16f16(ajt, gt[0], c0, 0, 0, 0);
        c1 = __builtin_amdgcn_mfma_f32_16x16x16f16(ajt, gt[1], c1, 0, 0, 0);
        c2 = __builtin_amdgcn_mfma_f32_16x16x16f16(ajt, gt[2], c2, 0, 0, 0);
        c3 = __builtin_amdgcn_mfma_f32_16x16x16f16(ajt, gt[3], c3, 0, 0, 0);
      }

      // ---- select by adj + leaky-relu + mask ----
      const int va[4] = {av.x, av.y, av.z, av.w};
      float sv[4];
#pragma unroll
      for (int r = 0; r < 4; ++r) {
        const float e = (va[r] == 1) ? c0[r] : (va[r] == 2) ? c1[r]
                       : (va[r] == 3) ? c2[r] : c3[r];
        sv[r] = (va[r] == 0) ? NEGINF : fmaxf(e, 0.2f * e);
      }
      if (jt == 18 && lg == 3) { sv[0] = PADV; sv[1] = PADV; sv[2] = PADV; sv[3] = PADV; }
      av = avn;

      // ---- PV h^T fragments: tr-reads issued here (c0..c3 dead),
      //      latency covered by the softmax VALU below ----
      const unsigned trb = ldsbase + (unsigned)(jt * 3584) + trlane;
      half4 hf[7];
#pragma unroll
      for (int t = 0; t < 7; ++t)
        asm volatile("ds_read_b64_tr_b16 %0, %1 offset:%2"
                     : "=v"(hf[t]) : "v"(trb), "i"(t * 512));

      // ---- online softmax (m shared across the 4 lane-groups of this i) ----
      float tmax = fmaxf(fmaxf(sv[0], sv[1]), fmaxf(sv[2], sv[3]));
      tmax = fmaxf(tmax, __shfl_xor(tmax, 16));
      tmax = fmaxf(tmax, __shfl_xor(tmax, 32));
      if (tmax > m) {
        const float f = __expf(m - tmax);
        m = tmax;
        lsum *= f;
#pragma unroll
        for (int t = 0; t < 7; ++t) {
          acc[t][0] *= f; acc[t][1] *= f; acc[t][2] *= f; acc[t][3] *= f;
        }
      }
      const float p0 = __expf(sv[0] - m), p1 = __expf(sv[1] - m);
      const float p2 = __expf(sv[2] - m), p3 = __expf(sv[3] - m);
      lsum += (p0 + p1) + (p2 + p3);
      half4 pb;
      pb[0] = (_Float16)p0; pb[1] = (_Float16)p1;
      pb[2] = (_Float16)p2; pb[3] = (_Float16)p3;

      // ---- PV: wait tr-reads; rule #18 fence so MFMAs can't hoist ----
      asm volatile("s_waitcnt lgkmcnt(0)" ::: "memory");
      __builtin_amdgcn_sched_barrier(0);
#pragma unroll
      for (int t = 0; t < 7; ++t)
        acc[t] = __builtin_amdgcn_mfma_f32_16x16x16f16(hf[t], pb, acc[t], 0, 0, 0);
    }

    // ---- epilogue: normalize + store ----
    lsum += __shfl_xor(lsum, 16);
    lsum += __shfl_xor(lsum, 32);
    const float rv = 1.f / lsum;
    if (irow < N_) {
      float* orow = OUT + ((size_t)b * N_ + irow) * E_;
#pragma unroll
      for (int t = 0; t < 7; ++t) {
        const int e0 = t * 16 + lg * 4;
        if (e0 < E_) {
          f32x4 o = acc[t];
          o[0] *= rv; o[1] *= rv; o[2] *= rv; o[3] *= rv;
          *(f32x4*)&orow[e0] = o;
        }
      }
    }
  }
}

extern "C" void kernel_launch(void* const* d_in, const int* in_sizes, int n_in,
                              void* d_out, int out_size, void* d_ws, size_t ws_size,
                              hipStream_t stream) {
  const float* H  = (const float*)d_in[0];
  const int*   AJ = (const int*)d_in[1];
  const float* A  = (const float*)d_in[2];
  float* OUT = (float*)d_out;

  (void)hipFuncSetAttribute(reinterpret_cast<const void*>(gat_flash4),
                            hipFuncAttributeMaxDynamicSharedMemorySize,
                            LDS_BYTES);
  gat_flash4<<<2 * B_, 512, LDS_BYTES, stream>>>(H, AJ, A, OUT);
}

// Round 7
// 97.107 us; speedup vs baseline: 1.8706x; 1.0824x over previous
//
#include <hip/hip_runtime.h>

// MFMA fragment layouts (gfx950, 16x16 family, verified m89):
//   A-frag (M16,K32): lane l holds A[row=l&15][k=(l>>4)*8+e], e=0..7
//   B-frag (K32,N16): lane l holds B[k=(l>>4)*8+e][col=l&15]
//   C/D:              col=l&15, row=(l>>4)*4+reg
//   K=16 variants: same with 4 elems, k=(l>>4)*4+e.
//
// h stored subtiled: hS[jt][et][j'][d'] = h[16*jt+j'][16*et+d'] (16x16 f16 = 512 B).
// ds_read_b64_tr_b16 (model verified by v6 passing): lane (lg,ll) addr =
// subtile + lg*128 + ll*8; HW transposes within each 16-lane group so elem
// e = subtile[lg*4+e][ll] = h[j0+lg*4+e][e0+ll] — the exact K16 A-frag.
//
// NOTE __launch_bounds__(512, 2), NOT (512, 4): the (512,4) bound made the
// compiler split 64 arch + 64 acc and scratch-spill the ~110-reg arch live
// set (v5/v6: VGPR_Count=64, WRITE_SIZE 59-146 MB vs 30 MB output). With
// (512,2) the same live set allocates spill-free (~124 regs, v3-verified);
// runtime residency is still 2 blocks/CU because 124<=128 VGPR allows
// 4 waves/SIMD and LDS is 69 KB.

typedef _Float16 half8 __attribute__((ext_vector_type(8)));
typedef _Float16 half4 __attribute__((ext_vector_type(4)));
typedef float f32x4 __attribute__((ext_vector_type(4)));

constexpr int B_ = 256, N_ = 300, E_ = 100;
constexpr float NEGINF = -9e15f;   // reference mask value
constexpr float PADV   = -3e38f;   // padding: exp(PADV - m) == 0 even vs NEGINF max

// LDS: hS subtiled [19][7][16][16] f16 = 68096 B @0 | A16 [4][128] f16 @68096 (1024 B)
constexpr int LDS_BYTES = 68096 + 1024;   // 69120 -> 2 blocks/CU

__global__ __launch_bounds__(512, 2)
void gat_flash5(const float* __restrict__ H, const int* __restrict__ ADJ,
                const float* __restrict__ A, float* __restrict__ OUT) {
  extern __shared__ char smraw[];
  _Float16* hS  = (_Float16*)smraw;
  _Float16* A16 = (_Float16*)(smraw + 68096);

  const int bid = blockIdx.x;
  const int b = bid >> 1, q = bid & 1;          // 2 blocks per batch (even/odd strips)
  const int tid = threadIdx.x;
  const int w = tid >> 6, lane = tid & 63;
  const int lg = lane >> 4, ll = lane & 15;

  const float* Hb  = H + (size_t)b * (N_ * E_);
  const int*   AJb = ADJ + (size_t)b * (N_ * N_);

  // ---------------- stage h into subtiled LDS (zero-padded) ----------------
  for (int u = tid; u < 304 * 14; u += 512) {
    const int j = u / 14, hr = u % 14;          // hr: 8-half chunk of d (d = hr*8+e)
    half8 v;
#pragma unroll
    for (int e = 0; e < 8; ++e) {
      const int d = hr * 8 + e;
      v[e] = (_Float16)((j < N_ && d < E_) ? Hb[j * E_ + d] : 0.f);
    }
    *(half8*)&hS[(((j >> 4) * 7 + (hr >> 1)) << 8) + ((j & 15) << 4) + ((hr & 1) << 3)] = v;
  }
  if (tid < 64) {
    const int k = tid >> 4, oct = tid & 15;
    half8 v;
#pragma unroll
    for (int e = 0; e < 8; ++e) {
      const int d = oct * 8 + e;
      v[e] = (_Float16)((d < E_) ? A[k * E_ + d] : 0.f);
    }
    *(half8*)&A16[k * 128 + oct * 8] = v;
  }
  __syncthreads();   // only barrier

  const unsigned ldsbase = (unsigned)(size_t)(void*)hS;     // low 32b = LDS offset
  const unsigned trlane  = (unsigned)(ll * 8 + lg * 128);   // natural per-lane addr

  // ============ per-wave independent 16-row i-strips (even/odd split) ======
  for (int tl = w; q + 2 * tl < 19; tl += 8) {
    const int s    = q + 2 * tl;
    const int irow = s * 16 + ll;
    const int irc  = irow < N_ ? irow : N_ - 1;

    // ---- G = h_i (.) A_k octets (B-operand fragments), per strip ----
    half8 g[3][4];
    half4 gt[4];
#pragma unroll
    for (int db = 0; db < 3; ++db) {
      const int doct = db * 4 + lg;
      const half8 hi = *(const half8*)&hS[((s * 7 + (doct >> 1)) << 8) + (ll << 4) + ((doct & 1) << 3)];
#pragma unroll
      for (int k = 0; k < 4; ++k)
        g[db][k] = hi * *(const half8*)&A16[k * 128 + doct * 8];
    }
    {
      const half4 hit = *(const half4*)&hS[((s * 7 + 6) << 8) + (ll << 4) + lg * 4];
#pragma unroll
      for (int k = 0; k < 4; ++k)
        gt[k] = hit * *(const half4*)&A16[k * 128 + 96 + lg * 4];
    }

    float m = PADV, lsum = 0.f;
    f32x4 acc[7];
#pragma unroll
    for (int t = 0; t < 7; ++t) acc[t] = (f32x4){0.f, 0.f, 0.f, 0.f};

    const int* ajrow = AJb + (size_t)irc * N_;
    int4 av = *(const int4*)(ajrow + lg * 4);

    for (int jt = 0; jt < 19; ++jt) {
      // ---- next tile's adj chunk (clamped; jt==18/lg==3 overridden) ----
      int4 avn = av;
      if (jt < 18) {
        int jc = jt * 16 + 16 + lg * 4;
        if (jc > N_ - 4) jc = N_ - 4;
        avn = *(const int4*)(ajrow + jc);
      }

      // ---- scores: S^T tile, 4 edge-type accumulators ----
      f32x4 c0 = {0.f, 0.f, 0.f, 0.f}, c1 = c0, c2 = c0, c3 = c0;
#pragma unroll
      for (int db = 0; db < 3; ++db) {
        const int doct = db * 4 + lg;
        const half8 aj = *(const half8*)&hS[((jt * 7 + (doct >> 1)) << 8) + (ll << 4) + ((doct & 1) << 3)];
        c0 = __builtin_amdgcn_mfma_f32_16x16x32_f16(aj, g[db][0], c0, 0, 0, 0);
        c1 = __builtin_amdgcn_mfma_f32_16x16x32_f16(aj, g[db][1], c1, 0, 0, 0);
        c2 = __builtin_amdgcn_mfma_f32_16x16x32_f16(aj, g[db][2], c2, 0, 0, 0);
        c3 = __builtin_amdgcn_mfma_f32_16x16x32_f16(aj, g[db][3], c3, 0, 0, 0);
      }
      {
        const half4 ajt = *(const half4*)&hS[((jt * 7 + 6) << 8) + (ll << 4) + lg * 4];
        c0 = __builtin_amdgcn_mfma_f32_16x16x16f16(ajt, gt[0], c0, 0, 0, 0);
        c1 = __builtin_amdgcn_mfma_f32_16x16x16f16(ajt, gt[1], c1, 0, 0, 0);
        c2 = __builtin_amdgcn_mfma_f32_16x16x16f16(ajt, gt[2], c2, 0, 0, 0);
        c3 = __builtin_amdgcn_mfma_f32_16x16x16f16(ajt, gt[3], c3, 0, 0, 0);
      }

      // ---- select by adj + leaky-relu + mask ----
      const int va[4] = {av.x, av.y, av.z, av.w};
      float sv[4];
#pragma unroll
      for (int r = 0; r < 4; ++r) {
        const float e = (va[r] == 1) ? c0[r] : (va[r] == 2) ? c1[r]
                       : (va[r] == 3) ? c2[r] : c3[r];
        sv[r] = (va[r] == 0) ? NEGINF : fmaxf(e, 0.2f * e);
      }
      if (jt == 18 && lg == 3) { sv[0] = PADV; sv[1] = PADV; sv[2] = PADV; sv[3] = PADV; }
      av = avn;

      // ---- online softmax (m shared across the 4 lane-groups of this i) ----
      float tmax = fmaxf(fmaxf(sv[0], sv[1]), fmaxf(sv[2], sv[3]));
      tmax = fmaxf(tmax, __shfl_xor(tmax, 16));
      tmax = fmaxf(tmax, __shfl_xor(tmax, 32));
      if (tmax > m) {
        const float f = __expf(m - tmax);
        m = tmax;
        lsum *= f;
#pragma unroll
        for (int t = 0; t < 7; ++t) {
          acc[t][0] *= f; acc[t][1] *= f; acc[t][2] *= f; acc[t][3] *= f;
        }
      }
      const float p0 = __expf(sv[0] - m), p1 = __expf(sv[1] - m);
      const float p2 = __expf(sv[2] - m), p3 = __expf(sv[3] - m);
      lsum += (p0 + p1) + (p2 + p3);
      half4 pb;
      pb[0] = (_Float16)p0; pb[1] = (_Float16)p1;
      pb[2] = (_Float16)p2; pb[3] = (_Float16)p3;

      // ---- PV h^T fragments: tr-reads issued late (short hf live range;
      //      latency hidden by TLP at 16 waves/CU) ----
      const unsigned trb = ldsbase + (unsigned)(jt * 3584) + trlane;
      half4 hf[7];
#pragma unroll
      for (int t = 0; t < 7; ++t)
        asm volatile("ds_read_b64_tr_b16 %0, %1 offset:%2"
                     : "=v"(hf[t]) : "v"(trb), "i"(t * 512));

      // ---- PV: wait tr-reads; rule #18 fence so MFMAs can't hoist ----
      asm volatile("s_waitcnt lgkmcnt(0)" ::: "memory");
      __builtin_amdgcn_sched_barrier(0);
#pragma unroll
      for (int t = 0; t < 7; ++t)
        acc[t] = __builtin_amdgcn_mfma_f32_16x16x16f16(hf[t], pb, acc[t], 0, 0, 0);
    }

    // ---- epilogue: normalize + store ----
    lsum += __shfl_xor(lsum, 16);
    lsum += __shfl_xor(lsum, 32);
    const float rv = 1.f / lsum;
    if (irow < N_) {
      float* orow = OUT + ((size_t)b * N_ + irow) * E_;
#pragma unroll
      for (int t = 0; t < 7; ++t) {
        const int e0 = t * 16 + lg * 4;
        if (e0 < E_) {
          f32x4 o = acc[t];
          o[0] *= rv; o[1] *= rv; o[2] *= rv; o[3] *= rv;
          *(f32x4*)&orow[e0] = o;
        }
      }
    }
  }
}

extern "C" void kernel_launch(void* const* d_in, const int* in_sizes, int n_in,
                              void* d_out, int out_size, void* d_ws, size_t ws_size,
                              hipStream_t stream) {
  const float* H  = (const float*)d_in[0];
  const int*   AJ = (const int*)d_in[1];
  const float* A  = (const float*)d_in[2];
  float* OUT = (float*)d_out;

  (void)hipFuncSetAttribute(reinterpret_cast<const void*>(gat_flash5),
                            hipFuncAttributeMaxDynamicSharedMemorySize,
                            LDS_BYTES);
  gat_flash5<<<2 * B_, 512, LDS_BYTES, stream>>>(H, AJ, A, OUT);
}

// Round 8
// 84.083 us; speedup vs baseline: 2.1603x; 1.1549x over previous
//
#include <hip/hip_runtime.h>

// MFMA fragment layouts (gfx950, 16x16 family, verified m89):
//   A-frag (M16,K32): lane l holds A[row=l&15][k=(l>>4)*8+e], e=0..7
//   B-frag (K32,N16): lane l holds B[k=(l>>4)*8+e][col=l&15]
//   C/D:              col=l&15, row=(l>>4)*4+reg
//   K=16 variants: same with 4 elems, k=(l>>4)*4+e.
//
// h stored subtiled: hS[jt][et][j'][d'] = h[16*jt+j'][16*et+d'] (16x16 f16 = 512 B).
// ds_read_b64_tr_b16 (verified v6): lane (lg,ll) addr = subtile + lg*128 + ll*8;
// HW transposes within each 16-lane group: elem e = subtile[lg*4+e][ll]
// = h[j0+lg*4+e][e0+ll] — exactly the K16 PV A-frag.
//
// Geometry: 640-thread blocks (10 waves), grid 512 (2 blocks/batch, even/odd
// strips). One wave = one 16-row strip (s = 2w+q) -> critical path 1 strip,
// no imbalance. LDS 69 KB -> 2 blocks/CU = 20 waves/CU = 5 waves/SIMD.
// __launch_bounds__ has NO min-waves arg: (512,2) builds measured 19% occ,
// (512,4) builds spilled (VGPR_Count 64, WRITE_SIZE 2-5x output) — both
// arms lose; default allocator with ~140-reg live set needs neither.

typedef _Float16 half8 __attribute__((ext_vector_type(8)));
typedef _Float16 half4 __attribute__((ext_vector_type(4)));
typedef float f32x4 __attribute__((ext_vector_type(4)));

constexpr int B_ = 256, N_ = 300, E_ = 100;
constexpr float NEGINF = -9e15f;   // reference mask value
constexpr float PADV   = -3e38f;   // padding: exp(PADV - m) == 0 even vs NEGINF max

// LDS: hS subtiled [19][7][16][16] f16 = 68096 B @0 | A16 [4][128] f16 @68096 (1024 B)
constexpr int LDS_BYTES = 68096 + 1024;   // 69120 -> 2 blocks/CU

__global__ __launch_bounds__(640)
void gat_flash6(const float* __restrict__ H, const int* __restrict__ ADJ,
                const float* __restrict__ A, float* __restrict__ OUT) {
  extern __shared__ char smraw[];
  _Float16* hS  = (_Float16*)smraw;
  _Float16* A16 = (_Float16*)(smraw + 68096);

  const int bid = blockIdx.x;
  const int b = bid >> 1, q = bid & 1;          // 2 blocks per batch (even/odd strips)
  const int tid = threadIdx.x;
  const int w = tid >> 6, lane = tid & 63;
  const int lg = lane >> 4, ll = lane & 15;

  const float* Hb  = H + (size_t)b * (N_ * E_);
  const int*   AJb = ADJ + (size_t)b * (N_ * N_);

  // ---------------- stage h into subtiled LDS (zero-padded) ----------------
  for (int u = tid; u < 304 * 14; u += 640) {
    const int j = u / 14, hr = u % 14;          // hr: 8-half chunk of d (d = hr*8+e)
    half8 v;
#pragma unroll
    for (int e = 0; e < 8; ++e) {
      const int d = hr * 8 + e;
      v[e] = (_Float16)((j < N_ && d < E_) ? Hb[j * E_ + d] : 0.f);
    }
    *(half8*)&hS[(((j >> 4) * 7 + (hr >> 1)) << 8) + ((j & 15) << 4) + ((hr & 1) << 3)] = v;
  }
  if (tid < 64) {
    const int k = tid >> 4, oct = tid & 15;
    half8 v;
#pragma unroll
    for (int e = 0; e < 8; ++e) {
      const int d = oct * 8 + e;
      v[e] = (_Float16)((d < E_) ? A[k * E_ + d] : 0.f);
    }
    *(half8*)&A16[k * 128 + oct * 8] = v;
  }
  __syncthreads();   // only barrier

  const unsigned ldsbase = (unsigned)(size_t)(void*)hS;     // low 32b = LDS offset
  const unsigned trlane  = (unsigned)(ll * 8 + lg * 128);   // per-lane tr addr

  // ================= one wave = one 16-row i-strip =========================
  const int s = 2 * w + q;
  if (s < 19) {
    const int irow = s * 16 + ll;
    const int irc  = irow < N_ ? irow : N_ - 1;

    // ---- G = h_i (.) A_k octets (B-operand fragments) ----
    half8 g[3][4];
    half4 gt[4];
#pragma unroll
    for (int db = 0; db < 3; ++db) {
      const int doct = db * 4 + lg;
      const half8 hi = *(const half8*)&hS[((s * 7 + (doct >> 1)) << 8) + (ll << 4) + ((doct & 1) << 3)];
#pragma unroll
      for (int k = 0; k < 4; ++k)
        g[db][k] = hi * *(const half8*)&A16[k * 128 + doct * 8];
    }
    {
      const half4 hit = *(const half4*)&hS[((s * 7 + 6) << 8) + (ll << 4) + lg * 4];
#pragma unroll
      for (int k = 0; k < 4; ++k)
        gt[k] = hit * *(const half4*)&A16[k * 128 + 96 + lg * 4];
    }

    float m = PADV, lsum = 0.f;
    f32x4 acc[7];
#pragma unroll
    for (int t = 0; t < 7; ++t) acc[t] = (f32x4){0.f, 0.f, 0.f, 0.f};

    const int* ajrow = AJb + (size_t)irc * N_;
    int4 av = *(const int4*)(ajrow + lg * 4);

    for (int jt = 0; jt < 19; ++jt) {
      // ---- next tile's adj chunk (clamped; jt==18/lg==3 overridden) ----
      int4 avn = av;
      if (jt < 18) {
        int jc = jt * 16 + 16 + lg * 4;
        if (jc > N_ - 4) jc = N_ - 4;
        avn = *(const int4*)(ajrow + jc);
      }

      // ---- scores: S^T tile, 4 edge-type accumulators ----
      f32x4 c0 = {0.f, 0.f, 0.f, 0.f}, c1 = c0, c2 = c0, c3 = c0;
#pragma unroll
      for (int db = 0; db < 3; ++db) {
        const int doct = db * 4 + lg;
        const half8 aj = *(const half8*)&hS[((jt * 7 + (doct >> 1)) << 8) + (ll << 4) + ((doct & 1) << 3)];
        c0 = __builtin_amdgcn_mfma_f32_16x16x32_f16(aj, g[db][0], c0, 0, 0, 0);
        c1 = __builtin_amdgcn_mfma_f32_16x16x32_f16(aj, g[db][1], c1, 0, 0, 0);
        c2 = __builtin_amdgcn_mfma_f32_16x16x32_f16(aj, g[db][2], c2, 0, 0, 0);
        c3 = __builtin_amdgcn_mfma_f32_16x16x32_f16(aj, g[db][3], c3, 0, 0, 0);
      }
      {
        const half4 ajt = *(const half4*)&hS[((jt * 7 + 6) << 8) + (ll << 4) + lg * 4];
        c0 = __builtin_amdgcn_mfma_f32_16x16x16f16(ajt, gt[0], c0, 0, 0, 0);
        c1 = __builtin_amdgcn_mfma_f32_16x16x16f16(ajt, gt[1], c1, 0, 0, 0);
        c2 = __builtin_amdgcn_mfma_f32_16x16x16f16(ajt, gt[2], c2, 0, 0, 0);
        c3 = __builtin_amdgcn_mfma_f32_16x16x16f16(ajt, gt[3], c3, 0, 0, 0);
      }

      // ---- PV h^T fragments: tr-reads issued early; latency covered by
      //      the select+softmax VALU below ----
      const unsigned trb = ldsbase + (unsigned)(jt * 3584) + trlane;
      half4 hf[7];
#pragma unroll
      for (int t = 0; t < 7; ++t)
        asm volatile("ds_read_b64_tr_b16 %0, %1 offset:%2"
                     : "=v"(hf[t]) : "v"(trb), "i"(t * 512));

      // ---- select by adj + leaky-relu + mask ----
      const int va[4] = {av.x, av.y, av.z, av.w};
      float sv[4];
#pragma unroll
      for (int r = 0; r < 4; ++r) {
        const float e = (va[r] == 1) ? c0[r] : (va[r] == 2) ? c1[r]
                       : (va[r] == 3) ? c2[r] : c3[r];
        sv[r] = (va[r] == 0) ? NEGINF : fmaxf(e, 0.2f * e);
      }
      if (jt == 18 && lg == 3) { sv[0] = PADV; sv[1] = PADV; sv[2] = PADV; sv[3] = PADV; }
      av = avn;

      // ---- online softmax (m shared across the 4 lane-groups of this i) ----
      float tmax = fmaxf(fmaxf(sv[0], sv[1]), fmaxf(sv[2], sv[3]));
      tmax = fmaxf(tmax, __shfl_xor(tmax, 16));
      tmax = fmaxf(tmax, __shfl_xor(tmax, 32));
      if (tmax > m) {
        const float f = __expf(m - tmax);
        m = tmax;
        lsum *= f;
#pragma unroll
        for (int t = 0; t < 7; ++t) {
          acc[t][0] *= f; acc[t][1] *= f; acc[t][2] *= f; acc[t][3] *= f;
        }
      }
      const float p0 = __expf(sv[0] - m), p1 = __expf(sv[1] - m);
      const float p2 = __expf(sv[2] - m), p3 = __expf(sv[3] - m);
      lsum += (p0 + p1) + (p2 + p3);
      half4 pb;
      pb[0] = (_Float16)p0; pb[1] = (_Float16)p1;
      pb[2] = (_Float16)p2; pb[3] = (_Float16)p3;

      // ---- PV: wait tr-reads; rule #18 fence so MFMAs can't hoist ----
      asm volatile("s_waitcnt lgkmcnt(0)" ::: "memory");
      __builtin_amdgcn_sched_barrier(0);
#pragma unroll
      for (int t = 0; t < 7; ++t)
        acc[t] = __builtin_amdgcn_mfma_f32_16x16x16f16(hf[t], pb, acc[t], 0, 0, 0);
    }

    // ---- epilogue: normalize + store ----
    lsum += __shfl_xor(lsum, 16);
    lsum += __shfl_xor(lsum, 32);
    const float rv = 1.f / lsum;
    if (irow < N_) {
      float* orow = OUT + ((size_t)b * N_ + irow) * E_;
#pragma unroll
      for (int t = 0; t < 7; ++t) {
        const int e0 = t * 16 + lg * 4;
        if (e0 < E_) {
          f32x4 o = acc[t];
          o[0] *= rv; o[1] *= rv; o[2] *= rv; o[3] *= rv;
          *(f32x4*)&orow[e0] = o;
        }
      }
    }
  }
}

extern "C" void kernel_launch(void* const* d_in, const int* in_sizes, int n_in,
                              void* d_out, int out_size, void* d_ws, size_t ws_size,
                              hipStream_t stream) {
  const float* H  = (const float*)d_in[0];
  const int*   AJ = (const int*)d_in[1];
  const float* A  = (const float*)d_in[2];
  float* OUT = (float*)d_out;

  (void)hipFuncSetAttribute(reinterpret_cast<const void*>(gat_flash6),
                            hipFuncAttributeMaxDynamicSharedMemorySize,
                            LDS_BYTES);
  gat_flash6<<<2 * B_, 640, LDS_BYTES, stream>>>(H, AJ, A, OUT);
}

// Round 10
// 81.087 us; speedup vs baseline: 2.2402x; 1.0369x over previous
//
#include <hip/hip_runtime.h>

// MFMA fragment layouts (gfx950, 16x16 family, verified m89):
//   A-frag (M16,K32): lane l holds A[row=l&15][k=(l>>4)*8+e], e=0..7
//   B-frag (K32,N16): lane l holds B[k=(l>>4)*8+e][col=l&15]
//   C/D:              col=l&15, row=(l>>4)*4+reg
//   K=16 variants: same with 4 elems, k=(l>>4)*4+e.
//
// h stored subtiled: hS[jt][et][j'][d'] = h[16*jt+j'][16*et+d'] (16x16 f16 = 512 B).
// ds_read_b64_tr_b16 (verified v6/v8): lane (lg,ll) addr = subtile + lg*128 + ll*8;
// HW transposes within each 16-lane group: elem e = subtile[lg*4+e][ll]
// = h[j0+lg*4+e][e0+ll] — exactly the K16 PV A-frag.
//
// v10 (from v8, after v9's launch-failure): paired j-tiles — ONE softmax +
// ONE fence per 32 j — but score tiles computed SEQUENTIALLY (4 MFMA chains
// live, not 8) to keep total regs ~launchable/spill-free. No setprio, no
// __any; rescale is branch-free (f=exp(m-nm), exp(0)=1 exact). Geometry
// unchanged: 640-thr blocks (10 waves), grid 512 (even/odd strips), one
// wave = one strip, LDS 69 KB. Total regs (~arch 100 + acc 44) -> 1 block/CU;
// the win is per-wave serial-overhead halving, not occupancy.

typedef _Float16 half8 __attribute__((ext_vector_type(8)));
typedef _Float16 half4 __attribute__((ext_vector_type(4)));
typedef float f32x4 __attribute__((ext_vector_type(4)));

constexpr int B_ = 256, N_ = 300, E_ = 100;
constexpr float NEGINF = -9e15f;   // reference mask value
constexpr float PADV   = -3e38f;   // padding: exp(PADV - m) == 0 even vs NEGINF max

// LDS: hS subtiled [19][7][16][16] f16 = 68096 B @0 | A16 [4][128] f16 @68096 (1024 B)
constexpr int LDS_BYTES = 68096 + 1024;

__global__ __launch_bounds__(640)
void gat_flash8(const float* __restrict__ H, const int* __restrict__ ADJ,
                const float* __restrict__ A, float* __restrict__ OUT) {
  extern __shared__ char smraw[];
  _Float16* hS  = (_Float16*)smraw;
  _Float16* A16 = (_Float16*)(smraw + 68096);

  const int bid = blockIdx.x;
  const int b = bid >> 1, q = bid & 1;          // 2 blocks per batch (even/odd strips)
  const int tid = threadIdx.x;
  const int w = tid >> 6, lane = tid & 63;
  const int lg = lane >> 4, ll = lane & 15;

  const float* Hb  = H + (size_t)b * (N_ * E_);
  const int*   AJb = ADJ + (size_t)b * (N_ * N_);

  // ---------------- stage h into subtiled LDS (zero-padded) ----------------
  for (int u = tid; u < 304 * 14; u += 640) {
    const int j = u / 14, hr = u % 14;          // hr: 8-half chunk of d (d = hr*8+e)
    half8 v;
#pragma unroll
    for (int e = 0; e < 8; ++e) {
      const int d = hr * 8 + e;
      v[e] = (_Float16)((j < N_ && d < E_) ? Hb[j * E_ + d] : 0.f);
    }
    *(half8*)&hS[(((j >> 4) * 7 + (hr >> 1)) << 8) + ((j & 15) << 4) + ((hr & 1) << 3)] = v;
  }
  if (tid < 64) {
    const int k = tid >> 4, oct = tid & 15;
    half8 v;
#pragma unroll
    for (int e = 0; e < 8; ++e) {
      const int d = oct * 8 + e;
      v[e] = (_Float16)((d < E_) ? A[k * E_ + d] : 0.f);
    }
    *(half8*)&A16[k * 128 + oct * 8] = v;
  }
  __syncthreads();   // only barrier

  const unsigned ldsbase = (unsigned)(size_t)(void*)hS;     // low 32b = LDS offset
  const unsigned trlane  = (unsigned)(ll * 8 + lg * 128);   // per-lane tr addr

  // ================= one wave = one 16-row i-strip =========================
  const int s = 2 * w + q;
  if (s < 19) {
    const int irow = s * 16 + ll;
    const int irc  = irow < N_ ? irow : N_ - 1;

    // ---- G = h_i (.) A_k octets (B-operand fragments) ----
    half8 g[3][4];
    half4 gt[4];
#pragma unroll
    for (int db = 0; db < 3; ++db) {
      const int doct = db * 4 + lg;
      const half8 hi = *(const half8*)&hS[((s * 7 + (doct >> 1)) << 8) + (ll << 4) + ((doct & 1) << 3)];
#pragma unroll
      for (int k = 0; k < 4; ++k)
        g[db][k] = hi * *(const half8*)&A16[k * 128 + doct * 8];
    }
    {
      const half4 hit = *(const half4*)&hS[((s * 7 + 6) << 8) + (ll << 4) + lg * 4];
#pragma unroll
      for (int k = 0; k < 4; ++k)
        gt[k] = hit * *(const half4*)&A16[k * 128 + 96 + lg * 4];
    }

    float m = PADV, lsum = 0.f;
    f32x4 acc[7];
#pragma unroll
    for (int t = 0; t < 7; ++t) acc[t] = (f32x4){0.f, 0.f, 0.f, 0.f};

    const int* ajrow = AJb + (size_t)irc * N_;
    int4 av0 = *(const int4*)(ajrow + lg * 4);          // tile 0 chunk
    int4 av1 = *(const int4*)(ajrow + 16 + lg * 4);     // tile 1 chunk

    // ============ paired j-tiles: jtA=2p, jtB=2p+1 (p=0..8, j<288) =========
    for (int p = 0; p < 9; ++p) {
      const int jtA = 2 * p, jtB = 2 * p + 1;

      // ---- prefetch next pair's adj chunks (clamped in-bounds; exact for
      //      p<8, garbage-but-safe at p=8 where tail reloads anyway) ----
      int jc0 = p * 32 + 32 + lg * 4; if (jc0 > N_ - 4) jc0 = N_ - 4;
      int jc1 = p * 32 + 48 + lg * 4; if (jc1 > N_ - 4) jc1 = N_ - 4;
      const int4 nv0 = *(const int4*)(ajrow + jc0);
      const int4 nv1 = *(const int4*)(ajrow + jc1);

      // ---- scores tile A (4 chains) ----
      f32x4 c0 = {0.f, 0.f, 0.f, 0.f}, c1 = c0, c2 = c0, c3 = c0;
#pragma unroll
      for (int db = 0; db < 3; ++db) {
        const int doct = db * 4 + lg;
        const half8 aj = *(const half8*)&hS[((jtA * 7 + (doct >> 1)) << 8) + (ll << 4) + ((doct & 1) << 3)];
        c0 = __builtin_amdgcn_mfma_f32_16x16x32_f16(aj, g[db][0], c0, 0, 0, 0);
        c1 = __builtin_amdgcn_mfma_f32_16x16x32_f16(aj, g[db][1], c1, 0, 0, 0);
        c2 = __builtin_amdgcn_mfma_f32_16x16x32_f16(aj, g[db][2], c2, 0, 0, 0);
        c3 = __builtin_amdgcn_mfma_f32_16x16x32_f16(aj, g[db][3], c3, 0, 0, 0);
      }
      {
        const half4 ajt = *(const half4*)&hS[((jtA * 7 + 6) << 8) + (ll << 4) + lg * 4];
        c0 = __builtin_amdgcn_mfma_f32_16x16x16f16(ajt, gt[0], c0, 0, 0, 0);
        c1 = __builtin_amdgcn_mfma_f32_16x16x16f16(ajt, gt[1], c1, 0, 0, 0);
        c2 = __builtin_amdgcn_mfma_f32_16x16x16f16(ajt, gt[2], c2, 0, 0, 0);
        c3 = __builtin_amdgcn_mfma_f32_16x16x16f16(ajt, gt[3], c3, 0, 0, 0);
      }
      const int vaA[4] = {av0.x, av0.y, av0.z, av0.w};
      float svA[4];
#pragma unroll
      for (int r = 0; r < 4; ++r) {
        const float e = (vaA[r] == 1) ? c0[r] : (vaA[r] == 2) ? c1[r]
                       : (vaA[r] == 3) ? c2[r] : c3[r];
        svA[r] = (vaA[r] == 0) ? NEGINF : fmaxf(e, 0.2f * e);
      }

      // ---- scores tile B (reuses chain registers after svA extracted) ----
      f32x4 d0 = {0.f, 0.f, 0.f, 0.f}, d1 = d0, d2 = d0, d3 = d0;
#pragma unroll
      for (int db = 0; db < 3; ++db) {
        const int doct = db * 4 + lg;
        const half8 aj = *(const half8*)&hS[((jtB * 7 + (doct >> 1)) << 8) + (ll << 4) + ((doct & 1) << 3)];
        d0 = __builtin_amdgcn_mfma_f32_16x16x32_f16(aj, g[db][0], d0, 0, 0, 0);
        d1 = __builtin_amdgcn_mfma_f32_16x16x32_f16(aj, g[db][1], d1, 0, 0, 0);
        d2 = __builtin_amdgcn_mfma_f32_16x16x32_f16(aj, g[db][2], d2, 0, 0, 0);
        d3 = __builtin_amdgcn_mfma_f32_16x16x32_f16(aj, g[db][3], d3, 0, 0, 0);
      }
      {
        const half4 ajt = *(const half4*)&hS[((jtB * 7 + 6) << 8) + (ll << 4) + lg * 4];
        d0 = __builtin_amdgcn_mfma_f32_16x16x16f16(ajt, gt[0], d0, 0, 0, 0);
        d1 = __builtin_amdgcn_mfma_f32_16x16x16f16(ajt, gt[1], d1, 0, 0, 0);
        d2 = __builtin_amdgcn_mfma_f32_16x16x16f16(ajt, gt[2], d2, 0, 0, 0);
        d3 = __builtin_amdgcn_mfma_f32_16x16x16f16(ajt, gt[3], d3, 0, 0, 0);
      }
      const int vaB[4] = {av1.x, av1.y, av1.z, av1.w};
      float svB[4];
#pragma unroll
      for (int r = 0; r < 4; ++r) {
        const float e = (vaB[r] == 1) ? d0[r] : (vaB[r] == 2) ? d1[r]
                       : (vaB[r] == 3) ? d2[r] : d3[r];
        svB[r] = (vaB[r] == 0) ? NEGINF : fmaxf(e, 0.2f * e);
      }
      av0 = nv0; av1 = nv1;

      // ---- PV h^T fragments: 14 tr-reads; latency covered by softmax ----
      const unsigned trbA = ldsbase + (unsigned)(jtA * 3584) + trlane;
      half4 hfA[7], hfB[7];
#pragma unroll
      for (int t = 0; t < 7; ++t)
        asm volatile("ds_read_b64_tr_b16 %0, %1 offset:%2"
                     : "=v"(hfA[t]) : "v"(trbA), "i"(t * 512));
#pragma unroll
      for (int t = 0; t < 7; ++t)
        asm volatile("ds_read_b64_tr_b16 %0, %1 offset:%2"
                     : "=v"(hfB[t]) : "v"(trbA), "i"(3584 + t * 512));

      // ---- ONE online-softmax update per 32 j (branch-free rescale) ----
      float tmax = fmaxf(fmaxf(fmaxf(svA[0], svA[1]), fmaxf(svA[2], svA[3])),
                         fmaxf(fmaxf(svB[0], svB[1]), fmaxf(svB[2], svB[3])));
      tmax = fmaxf(tmax, __shfl_xor(tmax, 16));
      tmax = fmaxf(tmax, __shfl_xor(tmax, 32));
      const float nm = fmaxf(m, tmax);
      const float f = __expf(m - nm);   // exp(0)==1 exactly when unchanged
      m = nm;
      lsum *= f;
#pragma unroll
      for (int t = 0; t < 7; ++t) {
        acc[t][0] *= f; acc[t][1] *= f; acc[t][2] *= f; acc[t][3] *= f;
      }
      const float pA0 = __expf(svA[0] - m), pA1 = __expf(svA[1] - m);
      const float pA2 = __expf(svA[2] - m), pA3 = __expf(svA[3] - m);
      const float pB0 = __expf(svB[0] - m), pB1 = __expf(svB[1] - m);
      const float pB2 = __expf(svB[2] - m), pB3 = __expf(svB[3] - m);
      lsum += ((pA0 + pA1) + (pA2 + pA3)) + ((pB0 + pB1) + (pB2 + pB3));
      half4 pbA, pbB;
      pbA[0] = (_Float16)pA0; pbA[1] = (_Float16)pA1;
      pbA[2] = (_Float16)pA2; pbA[3] = (_Float16)pA3;
      pbB[0] = (_Float16)pB0; pbB[1] = (_Float16)pB1;
      pbB[2] = (_Float16)pB2; pbB[3] = (_Float16)pB3;

      // ---- PV: one fence for all 14 tr-reads (rule #18) ----
      asm volatile("s_waitcnt lgkmcnt(0)" ::: "memory");
      __builtin_amdgcn_sched_barrier(0);
#pragma unroll
      for (int t = 0; t < 7; ++t) {
        acc[t] = __builtin_amdgcn_mfma_f32_16x16x16f16(hfA[t], pbA, acc[t], 0, 0, 0);
        acc[t] = __builtin_amdgcn_mfma_f32_16x16x16f16(hfB[t], pbB, acc[t], 0, 0, 0);
      }
    }

    // ================= tail tile jt = 18 (j = 288..299) ====================
    {
      const int jt = 18;
      int jc = 288 + lg * 4; if (jc > N_ - 4) jc = N_ - 4;
      const int4 av = *(const int4*)(ajrow + jc);

      f32x4 c0 = {0.f, 0.f, 0.f, 0.f}, c1 = c0, c2 = c0, c3 = c0;
#pragma unroll
      for (int db = 0; db < 3; ++db) {
        const int doct = db * 4 + lg;
        const half8 aj = *(const half8*)&hS[((jt * 7 + (doct >> 1)) << 8) + (ll << 4) + ((doct & 1) << 3)];
        c0 = __builtin_amdgcn_mfma_f32_16x16x32_f16(aj, g[db][0], c0, 0, 0, 0);
        c1 = __builtin_amdgcn_mfma_f32_16x16x32_f16(aj, g[db][1], c1, 0, 0, 0);
        c2 = __builtin_amdgcn_mfma_f32_16x16x32_f16(aj, g[db][2], c2, 0, 0, 0);
        c3 = __builtin_amdgcn_mfma_f32_16x16x32_f16(aj, g[db][3], c3, 0, 0, 0);
      }
      {
        const half4 ajt = *(const half4*)&hS[((jt * 7 + 6) << 8) + (ll << 4) + lg * 4];
        c0 = __builtin_amdgcn_mfma_f32_16x16x16f16(ajt, gt[0], c0, 0, 0, 0);
        c1 = __builtin_amdgcn_mfma_f32_16x16x16f16(ajt, gt[1], c1, 0, 0, 0);
        c2 = __builtin_amdgcn_mfma_f32_16x16x16f16(ajt, gt[2], c2, 0, 0, 0);
        c3 = __builtin_amdgcn_mfma_f32_16x16x16f16(ajt, gt[3], c3, 0, 0, 0);
      }

      const unsigned trb = ldsbase + (unsigned)(jt * 3584) + trlane;
      half4 hf[7];
#pragma unroll
      for (int t = 0; t < 7; ++t)
        asm volatile("ds_read_b64_tr_b16 %0, %1 offset:%2"
                     : "=v"(hf[t]) : "v"(trb), "i"(t * 512));

      const int va[4] = {av.x, av.y, av.z, av.w};
      float sv[4];
#pragma unroll
      for (int r = 0; r < 4; ++r) {
        const float e = (va[r] == 1) ? c0[r] : (va[r] == 2) ? c1[r]
                       : (va[r] == 3) ? c2[r] : c3[r];
        sv[r] = (va[r] == 0) ? NEGINF : fmaxf(e, 0.2f * e);
      }
      if (lg == 3) { sv[0] = PADV; sv[1] = PADV; sv[2] = PADV; sv[3] = PADV; }

      float tmax = fmaxf(fmaxf(sv[0], sv[1]), fmaxf(sv[2], sv[3]));
      tmax = fmaxf(tmax, __shfl_xor(tmax, 16));
      tmax = fmaxf(tmax, __shfl_xor(tmax, 32));
      const float nm = fmaxf(m, tmax);
      const float f = __expf(m - nm);
      m = nm;
      lsum *= f;
#pragma unroll
      for (int t = 0; t < 7; ++t) {
        acc[t][0] *= f; acc[t][1] *= f; acc[t][2] *= f; acc[t][3] *= f;
      }
      const float p0 = __expf(sv[0] - m), p1 = __expf(sv[1] - m);
      const float p2 = __expf(sv[2] - m), p3 = __expf(sv[3] - m);
      lsum += (p0 + p1) + (p2 + p3);
      half4 pb;
      pb[0] = (_Float16)p0; pb[1] = (_Float16)p1;
      pb[2] = (_Float16)p2; pb[3] = (_Float16)p3;

      asm volatile("s_waitcnt lgkmcnt(0)" ::: "memory");
      __builtin_amdgcn_sched_barrier(0);
#pragma unroll
      for (int t = 0; t < 7; ++t)
        acc[t] = __builtin_amdgcn_mfma_f32_16x16x16f16(hf[t], pb, acc[t], 0, 0, 0);
    }

    // ---- epilogue: normalize + store ----
    lsum += __shfl_xor(lsum, 16);
    lsum += __shfl_xor(lsum, 32);
    const float rv = 1.f / lsum;
    if (irow < N_) {
      float* orow = OUT + ((size_t)b * N_ + irow) * E_;
#pragma unroll
      for (int t = 0; t < 7; ++t) {
        const int e0 = t * 16 + lg * 4;
        if (e0 < E_) {
          f32x4 o = acc[t];
          o[0] *= rv; o[1] *= rv; o[2] *= rv; o[3] *= rv;
          *(f32x4*)&orow[e0] = o;
        }
      }
    }
  }
}

extern "C" void kernel_launch(void* const* d_in, const int* in_sizes, int n_in,
                              void* d_out, int out_size, void* d_ws, size_t ws_size,
                              hipStream_t stream) {
  const float* H  = (const float*)d_in[0];
  const int*   AJ = (const int*)d_in[1];
  const float* A  = (const float*)d_in[2];
  float* OUT = (float*)d_out;

  (void)hipFuncSetAttribute(reinterpret_cast<const void*>(gat_flash8),
                            hipFuncAttributeMaxDynamicSharedMemorySize,
                            LDS_BYTES);
  gat_flash8<<<2 * B_, 640, LDS_BYTES, stream>>>(H, AJ, A, OUT);
}